// Round 5
// baseline (287.623 us; speedup 1.0000x reference)
//
#include <hip/hip_runtime.h>

// SliceNApply: bilateral-grid trilinear slice + per-pixel 3x4 affine apply.
// FP32 tensors. B=4, C=12, D=8, Hg=Wg=16, H=W=1024.
//
// R5 = R4 with the inner loop reordered to kill scratch spills:
//  - R4 kept 12 live accumulators + weight arrays across a 48-FMA body ->
//    compiler spilled ~1.2KB/thread to scratch (hbm 557 MB, WRITE 7x out).
//  - Output channel o only needs coeff channels 4o..4o+3, so q (channel
//    group) is now the OUTER loop: 4 scalar accs live at a time, folded
//    into o[q] immediately. Same 12 ds_read_b128/px, same FMA count.
//  - Kept from R4 (verified): bf16 z-pair packing in LDS; wave=quadrant
//    mapping + ZSTRIDE=132 -> SQ_LDS_BANK_CONFLICT ~ 0; launch_bounds(256,3).

#define ZSTRIDE 132   // 9 cells * 12 ch = 108 dwords + 24 pad (132 % 32 == 4)

static __device__ __forceinline__ unsigned short f2bf(float f) {
    unsigned int u = __float_as_uint(f);
    u += ((u >> 16) & 1u) + 0x7FFFu;
    return (unsigned short)(u >> 16);
}
static __device__ __forceinline__ float bf_lo(unsigned int d) {
    return __uint_as_float(d << 16);
}
static __device__ __forceinline__ float bf_hi(unsigned int d) {
    return __uint_as_float(d & 0xFFFF0000u);
}

__global__ __launch_bounds__(256, 3) void slice_apply(
    const float* __restrict__ grid,   // [4][12][8][16][16]
    const float* __restrict__ guide,  // [4][1][1024][1024]
    const float* __restrict__ fr,     // [4][3][1024][1024]
    float* __restrict__ out)          // [4][3][1024][1024]
{
    __shared__ unsigned int lds[8 * ZSTRIDE];

    const int b     = blockIdx.y;
    const int tileX = blockIdx.x & 15;
    const int tileY = blockIdx.x >> 4;
    const int t     = threadIdx.x;

    int px[3], py[3];
#pragma unroll
    for (int j = 0; j < 3; ++j) {
        px[j] = min(max(tileX - 1 + j, 0), 15);
        py[j] = min(max(tileY - 1 + j, 0), 15);
    }

    // ---- stage grid slice into LDS, z-pair packed as bf16x2 ----
    for (int e = t; e < 8 * 9 * 12; e += 256) {
        const int c    = e % 12;
        const int cell = (e / 12) % 9;
        const int s    = e / 108;
        const int s2   = min(s + 1, 7);
        const int cb   = (b * 12 + c) * 8;
        const int sp   = py[cell / 3] * 16 + px[cell % 3];
        const float lo = grid[(cb + s)  * 256 + sp];
        const float hi = grid[(cb + s2) * 256 + sp];
        lds[s * ZSTRIDE + cell * 12 + c] =
            (unsigned int)f2bf(lo) | ((unsigned int)f2bf(hi) << 16);
    }
    __syncthreads();

    // wave = quadrant (32x32 px): by/bx wave-uniform
    const int w  = t >> 6;
    const int l  = t & 63;
    const int by = w >> 1;
    const int bx = w & 1;
    const int lx = bx * 32 + (l & 7) * 4;  // local x of 4-px strip
    const int rr = l >> 3;                 // row within 8-row stripe

    int cofs[4];
#pragma unroll
    for (int k = 0; k < 4; ++k) {
        cofs[k] = ((by + (k >> 1)) * 3 + (bx + (k & 1))) * 12;
    }

#pragma unroll
    for (int it = 0; it < 4; ++it) {
        const int ly = by * 32 + it * 8 + rr;   // tile-local y
        const int y  = tileY * 64 + ly;
        const float wy = ((float)ly + 0.5f) * 0.015625f + (0.5f - (float)by);
        const float v1 = wy, v0 = 1.0f - wy;

        const int gofs = (b * 1024 + y) * 1024 + tileX * 64 + lx;
        const int fofs = ((b * 3) * 1024 + y) * 1024 + tileX * 64 + lx;

        const float4 gv  = *reinterpret_cast<const float4*>(guide + gofs);
        const float4 f0v = *reinterpret_cast<const float4*>(fr + fofs);
        const float4 f1v = *reinterpret_cast<const float4*>(fr + fofs + 1048576);
        const float4 f2v = *reinterpret_cast<const float4*>(fr + fofs + 2097152);

        const float gva[4] = {gv.x, gv.y, gv.z, gv.w};
        const float fa0[4] = {f0v.x, f0v.y, f0v.z, f0v.w};
        const float fa1[4] = {f1v.x, f1v.y, f1v.z, f1v.w};
        const float fa2[4] = {f2v.x, f2v.y, f2v.z, f2v.w};

        float o0a[4], o1a[4], o2a[4];

#pragma unroll
        for (int p = 0; p < 4; ++p) {
            const float g  = gva[p];
            const float gz = g * 8.0f - 0.5f;
            int s = (int)floorf(gz);
            s = min(max(s, 0), 7);
            const float wz = fmaxf(gz - (float)s, 0.0f);
            const float zl = 1.0f - wz, zh = wz;
            const int sbase = s * ZSTRIDE;

            const float wx = ((float)(lx + p) + 0.5f) * 0.015625f +
                             (0.5f - (float)bx);
            const float u1 = wx, u0 = 1.0f - wx;

            // per-corner weights (8 regs), computed once per pixel
            float wl[4], wh[4];
#pragma unroll
            for (int k = 0; k < 4; ++k) {
                const float wgt = ((k >> 1) ? v1 : v0) * ((k & 1) ? u1 : u0);
                wl[k] = wgt * zl;
                wh[k] = wgt * zh;
            }

            const float f0 = fa0[p], f1 = fa1[p], f2 = fa2[p];
            float o[3];

            // q = output channel group OUTER: only 4 accumulators live
#pragma unroll
            for (int q = 0; q < 3; ++q) {
                float a0 = 0.0f, a1 = 0.0f, a2 = 0.0f, a3 = 0.0f;
#pragma unroll
                for (int k = 0; k < 4; ++k) {
                    const uint4 dq = *reinterpret_cast<const uint4*>(
                        &lds[sbase + cofs[k] + q * 4]);
                    a0 = fmaf(wl[k], bf_lo(dq.x), a0);
                    a0 = fmaf(wh[k], bf_hi(dq.x), a0);
                    a1 = fmaf(wl[k], bf_lo(dq.y), a1);
                    a1 = fmaf(wh[k], bf_hi(dq.y), a1);
                    a2 = fmaf(wl[k], bf_lo(dq.z), a2);
                    a2 = fmaf(wh[k], bf_hi(dq.z), a2);
                    a3 = fmaf(wl[k], bf_lo(dq.w), a3);
                    a3 = fmaf(wh[k], bf_hi(dq.w), a3);
                }
                o[q] = fmaf(a0, f0, fmaf(a1, f1, fmaf(a2, f2, a3)));
            }

            o0a[p] = o[0];
            o1a[p] = o[1];
            o2a[p] = o[2];
        }

        const float4 O0 = {o0a[0], o0a[1], o0a[2], o0a[3]};
        const float4 O1 = {o1a[0], o1a[1], o1a[2], o1a[3]};
        const float4 O2 = {o2a[0], o2a[1], o2a[2], o2a[3]};
        *reinterpret_cast<float4*>(out + fofs)           = O0;
        *reinterpret_cast<float4*>(out + fofs + 1048576) = O1;
        *reinterpret_cast<float4*>(out + fofs + 2097152) = O2;
    }
}

extern "C" void kernel_launch(void* const* d_in, const int* in_sizes, int n_in,
                              void* d_out, int out_size, void* d_ws, size_t ws_size,
                              hipStream_t stream) {
    const float* grid  = (const float*)d_in[0];
    const float* guide = (const float*)d_in[1];
    const float* fr    = (const float*)d_in[2];
    float* out = (float*)d_out;

    dim3 g(256, 4);   // 16x16 tiles of 64x64 px, 4 batches
    dim3 blk(256);
    hipLaunchKernelGGL(slice_apply, g, blk, 0, stream, grid, guide, fr, out);
}

// Round 6
// 123.306 us; speedup vs baseline: 2.3326x; 2.3326x over previous
//
#include <hip/hip_runtime.h>

// SliceNApply: bilateral-grid trilinear slice + per-pixel 3x4 affine apply.
// FP32 tensors. B=4, C=12, D=8, Hg=Wg=16, H=W=1024.
//
// R6: scratch-proof rewrite of the compute phase.
//   Evidence: R3-R5 all show FETCH > total input bytes (impossible for
//   genuine input reads: each line is touched once by one tile) + WRITE
//   7.5x output, at healthy VGPR=84 -> local arrays were demoted to
//   scratch (dynamic indexing when a loop level fails to unroll), not
//   pressure spills. Fix: ZERO local arrays, flat 16-iter loop, all
//   scalars -> nothing the compiler CAN demote.
//   Mapping: 1 px/lane; wave = its quadrant's 32x2-px strip per iter.
//   Kept (verified R2-R5): bf16 z-pair packing (12 ds_read_b128/px),
//   quadrant waves + ZSTRIDE=132 -> SQ_LDS_BANK_CONFLICT ~ 0,
//   __launch_bounds__(256,3) (170-VGPR budget, no pressure spills).

#define ZSTRIDE 132   // 9 cells * 12 ch = 108 dwords + 24 pad (132 % 32 == 4)

static __device__ __forceinline__ unsigned short f2bf(float f) {
    unsigned int u = __float_as_uint(f);
    u += ((u >> 16) & 1u) + 0x7FFFu;
    return (unsigned short)(u >> 16);
}
static __device__ __forceinline__ float bf_lo(unsigned int d) {
    return __uint_as_float(d << 16);
}
static __device__ __forceinline__ float bf_hi(unsigned int d) {
    return __uint_as_float(d & 0xFFFF0000u);
}

// one corner's 4-channel fused multiply-accumulate (all scalar refs)
static __device__ __forceinline__ void corner_fma(
    const unsigned int* __restrict__ cp, float wl, float wh,
    float& a0, float& a1, float& a2, float& a3)
{
    const uint4 d = *reinterpret_cast<const uint4*>(cp);
    a0 = fmaf(wl, bf_lo(d.x), a0); a0 = fmaf(wh, bf_hi(d.x), a0);
    a1 = fmaf(wl, bf_lo(d.y), a1); a1 = fmaf(wh, bf_hi(d.y), a1);
    a2 = fmaf(wl, bf_lo(d.z), a2); a2 = fmaf(wh, bf_hi(d.z), a2);
    a3 = fmaf(wl, bf_lo(d.w), a3); a3 = fmaf(wh, bf_hi(d.w), a3);
}

__global__ __launch_bounds__(256, 3) void slice_apply(
    const float* __restrict__ grid,   // [4][12][8][16][16]
    const float* __restrict__ guide,  // [4][1][1024][1024]
    const float* __restrict__ fr,     // [4][3][1024][1024]
    float* __restrict__ out)          // [4][3][1024][1024]
{
    __shared__ __align__(16) unsigned int lds[8 * ZSTRIDE];

    const int b     = blockIdx.y;
    const int tileX = blockIdx.x & 15;
    const int tileY = blockIdx.x >> 4;
    const int t     = threadIdx.x;

    // ---- stage grid slice into LDS, z-pair packed as bf16x2 ----
    {
        const int py0 = min(max(tileY - 1, 0), 15);
        const int py1 = tileY;
        const int py2 = min(tileY + 1, 15);
        const int px0 = min(max(tileX - 1, 0), 15);
        const int px1 = tileX;
        const int px2 = min(tileX + 1, 15);
        for (int e = t; e < 8 * 9 * 12; e += 256) {
            const int c    = e % 12;
            const int cell = (e / 12) % 9;
            const int s    = e / 108;
            const int s2   = min(s + 1, 7);
            const int gy3  = cell / 3;
            const int gx3  = cell % 3;
            const int ry = (gy3 == 0) ? py0 : ((gy3 == 1) ? py1 : py2);
            const int rx = (gx3 == 0) ? px0 : ((gx3 == 1) ? px1 : px2);
            const int cb = (b * 12 + c) * 8;
            const int sp = ry * 16 + rx;
            const float lo = grid[(cb + s)  * 256 + sp];
            const float hi = grid[(cb + s2) * 256 + sp];
            lds[s * ZSTRIDE + cell * 12 + c] =
                (unsigned int)f2bf(lo) | ((unsigned int)f2bf(hi) << 16);
        }
    }
    __syncthreads();

    // wave = quadrant (32x32 px); lane -> 1 px: 32 lanes span x, 2 sub-rows
    const int w   = t >> 6;
    const int l   = t & 63;
    const int by  = w >> 1;          // wave-uniform
    const int bx  = w & 1;           // wave-uniform
    const int lxq = l & 31;          // x within quadrant
    const int sub = l >> 5;          // row-pair select

    const int xg = tileX * 64 + bx * 32 + lxq;          // global x
    const float wx = ((float)(bx * 32 + lxq) + 0.5f) * 0.015625f +
                     (0.5f - (float)bx);
    const float u1 = wx, u0 = 1.0f - wx;

    // corner dword offsets: four named scalars (NOT an array)
    const int cof0 = ((by + 0) * 3 + (bx + 0)) * 12;
    const int cof1 = ((by + 0) * 3 + (bx + 1)) * 12;
    const int cof2 = ((by + 1) * 3 + (bx + 0)) * 12;
    const int cof3 = ((by + 1) * 3 + (bx + 1)) * 12;

    const int ybase = tileY * 64 + by * 32;

    for (int i = 0; i < 16; ++i) {
        const int ly = by * 32 + i * 2 + sub;           // tile-local y
        const int y  = ybase - by * 32 + ly;            // = tileY*64 + ly
        const float wy = ((float)ly + 0.5f) * 0.015625f + (0.5f - (float)by);
        const float v1 = wy, v0 = 1.0f - wy;

        const int gofs = (b * 1024 + y) * 1024 + xg;
        const int fofs = ((b * 3) * 1024 + y) * 1024 + xg;

        const float g  = guide[gofs];
        const float f0 = fr[fofs];
        const float f1 = fr[fofs + 1048576];
        const float f2 = fr[fofs + 2097152];

        const float gz = g * 8.0f - 0.5f;
        int s = (int)floorf(gz);
        s = min(max(s, 0), 7);
        const float wz = fmaxf(gz - (float)s, 0.0f);
        const float zl = 1.0f - wz, zh = wz;
        const unsigned int* sb = &lds[s * ZSTRIDE];

        const float w00 = v0 * u0, w01 = v0 * u1;
        const float w10 = v1 * u0, w11 = v1 * u1;
        const float wl0 = w00 * zl, wh0 = w00 * zh;
        const float wl1 = w01 * zl, wh1 = w01 * zh;
        const float wl2 = w10 * zl, wh2 = w10 * zh;
        const float wl3 = w11 * zl, wh3 = w11 * zh;

        float o0, o1, o2;
        {
            float a0 = 0.f, a1 = 0.f, a2 = 0.f, a3 = 0.f;
            corner_fma(sb + cof0, wl0, wh0, a0, a1, a2, a3);
            corner_fma(sb + cof1, wl1, wh1, a0, a1, a2, a3);
            corner_fma(sb + cof2, wl2, wh2, a0, a1, a2, a3);
            corner_fma(sb + cof3, wl3, wh3, a0, a1, a2, a3);
            o0 = fmaf(a0, f0, fmaf(a1, f1, fmaf(a2, f2, a3)));
        }
        {
            float a0 = 0.f, a1 = 0.f, a2 = 0.f, a3 = 0.f;
            corner_fma(sb + cof0 + 4, wl0, wh0, a0, a1, a2, a3);
            corner_fma(sb + cof1 + 4, wl1, wh1, a0, a1, a2, a3);
            corner_fma(sb + cof2 + 4, wl2, wh2, a0, a1, a2, a3);
            corner_fma(sb + cof3 + 4, wl3, wh3, a0, a1, a2, a3);
            o1 = fmaf(a0, f0, fmaf(a1, f1, fmaf(a2, f2, a3)));
        }
        {
            float a0 = 0.f, a1 = 0.f, a2 = 0.f, a3 = 0.f;
            corner_fma(sb + cof0 + 8, wl0, wh0, a0, a1, a2, a3);
            corner_fma(sb + cof1 + 8, wl1, wh1, a0, a1, a2, a3);
            corner_fma(sb + cof2 + 8, wl2, wh2, a0, a1, a2, a3);
            corner_fma(sb + cof3 + 8, wl3, wh3, a0, a1, a2, a3);
            o2 = fmaf(a0, f0, fmaf(a1, f1, fmaf(a2, f2, a3)));
        }

        out[fofs]           = o0;
        out[fofs + 1048576] = o1;
        out[fofs + 2097152] = o2;
    }
}

extern "C" void kernel_launch(void* const* d_in, const int* in_sizes, int n_in,
                              void* d_out, int out_size, void* d_ws, size_t ws_size,
                              hipStream_t stream) {
    const float* grid  = (const float*)d_in[0];
    const float* guide = (const float*)d_in[1];
    const float* fr    = (const float*)d_in[2];
    float* out = (float*)d_out;

    dim3 g(256, 4);   // 16x16 tiles of 64x64 px, 4 batches
    dim3 blk(256);
    hipLaunchKernelGGL(slice_apply, g, blk, 0, stream, grid, guide, fr, out);
}